// Round 7
// baseline (611.746 us; speedup 1.0000x reference)
//
#include <hip/hip_runtime.h>
#include <hip/hip_bf16.h>

#define N_NODES   50000
#define N_REL     16
#define HID       128
#define N_EDGES   1600000
#define N_TILES   3125          // N_NODES/16
#define N_BINS    800000        // fine bins (tile, rel, m)
#define N_RUNS    50000         // (tile, rel) runs of 16 fine bins
#define N_SCANBLK 49            // ceil(N_RUNS/1024)
#define N_MBLK    1563          // ceil(3125/2): M=32 per block
#define PAYLOAD_CAP 2400064     // E + 50000*15 pad worst case + slack
#define BS_LAYER  278528        // (16 rel + root)*4kk*8cb frags * 512 ushorts
#define AG_STRIDE 136           // ushorts per agg row (272 B, 16-B aligned)

typedef unsigned short ushort_t;
typedef __attribute__((ext_vector_type(8))) short short8;
typedef __attribute__((ext_vector_type(4))) float f32x4;

union BF2U { __hip_bfloat162 h; unsigned u; };

__device__ __forceinline__ unsigned pack_bf16_2(float x, float y) {
  BF2U c; c.h = __float22bfloat162_rn(make_float2(x, y));
  return c.u;
}

// barrier WITHOUT vmcnt drain: LDS ops drained (cross-wave visibility +
// dbuf safety), but in-flight global prefetches keep flying. This is the
// fix for __syncthreads' implicit s_waitcnt vmcnt(0) defeating the
// producer pipeline (m97-plateau mechanism).
__device__ __forceinline__ void lds_barrier() {
  asm volatile("s_waitcnt lgkmcnt(0)\n\ts_barrier" ::: "memory");
}

// ---------------- setup kernels ----------------

__global__ __launch_bounds__(256) void k_hist(const int* __restrict__ ei,
                                              const int* __restrict__ et,
                                              int* __restrict__ cnt,
                                              int* __restrict__ rank) {
  int e = blockIdx.x * 256 + threadIdx.x;   // grid covers E exactly
  int tgt = ei[N_EDGES + e];
  int r   = et[e];
  int key = ((tgt >> 4) << 8) | (r << 4) | (tgt & 15);
  rank[e] = atomicAdd(&cnt[key], 1);        // rank within bin falls out free
}

// per-run real total -> padded-to-16 total (into run_start array, pre-scan)
__global__ __launch_bounds__(256) void k_runpad(const int* __restrict__ cnt,
                                                int* __restrict__ padtot) {
  int r = blockIdx.x * 256 + threadIdx.x;
  if (r >= N_RUNS) return;
  const int4* c4 = (const int4*)(cnt + r * 16);
  int s = 0;
#pragma unroll
  for (int j = 0; j < 4; ++j) { int4 v = c4[j]; s += v.x + v.y + v.z + v.w; }
  padtot[r] = (s + 15) & ~15;
}

__global__ __launch_bounds__(256) void k_btot(const int* __restrict__ in,
                                              int* __restrict__ totals, int n) {
  __shared__ int s[256];
  int t = threadIdx.x, b = blockIdx.x;
  int sum = 0;
  for (int j = 0; j < 4; ++j) {
    int idx = b * 1024 + j * 256 + t;
    sum += (idx < n) ? in[idx] : 0;
  }
  s[t] = sum; __syncthreads();
  for (int ofs = 128; ofs > 0; ofs >>= 1) {
    if (t < ofs) s[t] += s[t + ofs];
    __syncthreads();
  }
  if (t == 0) totals[b] = s[0];
}

__global__ __launch_bounds__(1024) void k_scan_totals(int* totals, int* endp, int nblk) {
  __shared__ int s[1024];
  int t = threadIdx.x;
  int v = (t < nblk) ? totals[t] : 0;
  s[t] = v; __syncthreads();
  for (int ofs = 1; ofs < 1024; ofs <<= 1) {
    int x = (t >= ofs) ? s[t - ofs] : 0;
    __syncthreads();
    s[t] += x;
    __syncthreads();
  }
  if (t < nblk) totals[t] = s[t] - v;      // exclusive block offsets
  if (t == nblk - 1) *endp = s[t];         // grand total (padded edge count)
}

__global__ __launch_bounds__(1024) void k_scan_within(int* __restrict__ a,
                                                      const int* __restrict__ totals,
                                                      int n) {
  __shared__ int s[1024];
  int t = threadIdx.x, blk = blockIdx.x;
  int b = blk * 1024 + t;
  int v = (b < n) ? a[b] : 0;
  s[t] = v; __syncthreads();
  for (int ofs = 1; ofs < 1024; ofs <<= 1) {
    int x = (t >= ofs) ? s[t - ofs] : 0;
    __syncthreads();
    s[t] += x;
    __syncthreads();
  }
  if (b < n) a[b] = totals[blk] + s[t] - v;   // exclusive padded offsets
}

// fine-bin start offsets within each run + dummy-fill the pad region
__global__ __launch_bounds__(256) void k_fineoff(const int* __restrict__ cnt,
                                                 const int* __restrict__ run_start,
                                                 int* __restrict__ fine_start,
                                                 unsigned* __restrict__ payload) {
  int r = blockIdx.x * 256 + threadIdx.x;
  if (r >= N_RUNS) return;
  int base = run_start[r];
  int e1   = run_start[r + 1];
  int pfx = 0;
  for (int i = 0; i < 16; ++i) {
    fine_start[r * 16 + i] = base + pfx;
    pfx += cnt[r * 16 + i];
  }
  const unsigned dummy = ((unsigned)N_NODES << 16) | (1u << 4) | 15u;
  for (int j = base + pfx; j < e1; ++j) payload[j] = dummy;  // m=15, zero row
}

// payload = src:31..16 | bin_cnt:15..4 | m:3..0 — atomic-free placement
__global__ __launch_bounds__(256) void k_sort(const int* __restrict__ ei,
                                              const int* __restrict__ et,
                                              const int* __restrict__ cnt,
                                              const int* __restrict__ fine_start,
                                              const int* __restrict__ rank,
                                              unsigned* __restrict__ payload) {
  int e = blockIdx.x * 256 + threadIdx.x;
  int src = ei[e];
  int tgt = ei[N_EDGES + e];
  int r   = et[e];
  int key = ((tgt >> 4) << 8) | (r << 4) | (tgt & 15);
  int c = cnt[key]; c = c > 4095 ? 4095 : c;
  int pos = fine_start[key] + rank[e];
  payload[pos] = ((unsigned)src << 16) | ((unsigned)c << 4) | (unsigned)(tgt & 15);
}

// Bs fragment-ordered: frag = ((r*4+kk)*8+cb), r 0..16 (16=root); within frag
// 64 lanes x 8 bf16: lane -> col cb*16+(lane&15), k = kk*32+(lane>>4)*8+j.
// Thread = (l, frag, lane): per j, the 64 lanes read 4 FULLY-USED 64-B lines
// (coalesced); 16-B contiguous store. (Old version strided 512 B -> 16x
// read overfetch.)
__global__ __launch_bounds__(256) void k_bt(const float* __restrict__ W,
                                            const float* __restrict__ root,
                                            ushort_t* __restrict__ Bs) {
  int idx = blockIdx.x * 256 + threadIdx.x;    // 3*544*64 = 104448 exact
  int lane = idx & 63;
  int fl   = idx >> 6;                          // l*544 + frag
  int frag = fl % 544;
  int l    = fl / 544;
  int cb = frag & 7, kk = (frag >> 3) & 3, r = frag >> 5;
  int col = cb * 16 + (lane & 15);
  int d0  = kk * 32 + (lane >> 4) * 8;
  const float* srcp = (r < 16)
      ? W + ((size_t)(l * N_REL + r) * HID + d0) * HID + col
      : root + ((size_t)l * HID + d0) * HID + col;
  ushort_t out[8];
#pragma unroll
  for (int j = 0; j < 8; ++j) {
    union { __hip_bfloat16 h; ushort_t u; } c;
    c.h = __float2bfloat16(srcp[(size_t)j * HID]);
    out[j] = c.u;
  }
  *(short8*)(Bs + ((size_t)fl << 9) + lane * 8) = *(short8*)out;
}

__global__ __launch_bounds__(256) void k_xh(const float* __restrict__ xin,
                                            ushort_t* __restrict__ xh) {
  int i = blockIdx.x * 256 + threadIdx.x;      // grid = N*H/4 exact
  float4 v = ((const float4*)xin)[i];
  uint2 u;
  u.x = pack_bf16_2(v.x, v.y);
  u.y = pack_bf16_2(v.z, v.w);
  ((uint2*)xh)[i] = u;
}

// zero the dummy node row (row N_NODES) of both ping-pong buffers
__global__ __launch_bounds__(256) void k_zrow(ushort_t* xa, ushort_t* xb) {
  int t = threadIdx.x;
  if (t < 128) xa[(size_t)N_NODES * HID + t] = 0;
  else         xb[(size_t)N_NODES * HID + (t - 128)] = 0;
}

// ---------------- fused per-layer kernel: producer/consumer waves ----------
// Block = 32 nodes (2 tiles), 4 waves. Waves 0,1 = PRODUCERS (rel 2s+p at
// step s), register-RLE into double-buffered LDS agg. Waves 2,3 = CONSUMERS
// (B frags + MFMA). lds_barrier (lgkmcnt-only) lets prefetched gathers fly
// across the step barrier; b0/b1 of both runs + b2 prefetched per step.

__global__ __launch_bounds__(256, 4) void k_main(const ushort_t* __restrict__ xh,
                                                 ushort_t* __restrict__ xh_out,
                                                 float* __restrict__ fout,
                                                 const ushort_t* __restrict__ Bs,
                                                 const float* __restrict__ bias,
                                                 const int* __restrict__ run_start,
                                                 const unsigned* __restrict__ payload,
                                                 int write_f32) {
  __shared__ alignas(16) ushort_t agg[2][2][32][AG_STRIDE];   // 34.8 KB

  const int tile0 = blockIdx.x * 2;
  const int tid   = threadIdx.x;
  const int wave  = tid >> 6;
  const int lane  = tid & 63;
  const int m16   = lane & 15;
  const int q     = lane >> 4;
  const unsigned* xh32 = (const unsigned*)xh;

  if (wave < 2) {
    // ======================= PRODUCER =======================
    const int p = wave;
    // run bounds, 32 values lane-parallel: lane = s*4 + t*2 + h
    int ebv = 0;
    {
      int s8 = lane >> 2, t2 = (lane >> 1) & 1, h = lane & 1;
      int tt = tile0 + t2;
      int idx = (tt < N_TILES) ? (tt * 16 + s8 * 2 + p + h) : N_RUNS;
      if (lane < 32) ebv = run_start[idx];
    }

#define ISSUE16(DST, PV, JB)                                                  \
    _Pragma("unroll")                                                         \
    for (int k1 = 0; k1 < 16; ++k1) {                                         \
      unsigned spq = (unsigned)__builtin_amdgcn_readlane(PV, (JB) + k1);      \
      DST[k1] = xh32[(spq >> 16) * 64 + lane];                                \
    }

#define FLUSHM(TB, BUF)                                                       \
    if (mcur >= 0) {                                                          \
      float sc = __builtin_amdgcn_rcpf((float)scnt);                          \
      *(unsigned*)&agg[BUF][p][(TB) + mcur][lane * 2] =                       \
          pack_bf16_2(a0 * sc, a1 * sc);                                      \
    }

#define CONSUME1(SPK, XV, TB, BUF)                                            \
    {                                                                         \
      int mk = (int)((SPK) & 15u);                                            \
      if (mk != mcur) {                                                       \
        FLUSHM(TB, BUF);                                                      \
        mcur = mk; scnt = (int)(((SPK) >> 4) & 4095u);                        \
        a0 = 0.f; a1 = 0.f;                                                   \
      }                                                                       \
      a0 += __uint_as_float((XV) << 16);                                      \
      a1 += __uint_as_float((XV) & 0xffff0000u);                              \
    }

#define CONS16(PV, JB, SLOT, TB, BUF)                                         \
    _Pragma("unroll")                                                         \
    for (int k2 = 0; k2 < 16; ++k2) {                                         \
      unsigned spk = (unsigned)__builtin_amdgcn_readlane(PV, (JB) + k2);      \
      CONSUME1(spk, SLOT[k2], TB, BUF);                                       \
    }

// run consume: b0,b1 prefetched in B0,B1; b2 prefetched in xqE; b3 + >64 rare
#define RUNX(PV, E0, E1, CNT, B0, B1, TB)                                     \
    {                                                                         \
      int mcur = -1, scnt = 1;                                                \
      float a0 = 0.f, a1 = 0.f;                                               \
      if ((CNT) > 0) {                                                        \
        CONS16(PV, 0, B0, TB, buf);                                           \
        if ((CNT) > 16) {                                                     \
          CONS16(PV, 16, B1, TB, buf);                                        \
          if ((CNT) > 32) {                                                   \
            CONS16(PV, 32, xqE, TB, buf);                                     \
            if ((CNT) > 48) {                                                 \
              ISSUE16(xqE, PV, 48);                                           \
              CONS16(PV, 48, xqE, TB, buf);                                   \
            }                                                                 \
          }                                                                   \
        }                                                                     \
        for (int c0 = (E0) + 64; c0 < (E1); c0 += 16) { /* very rare */       \
          int pvx = (int)payload[c0 + lane];                                  \
          ISSUE16(xqE, pvx, 0);                                               \
          CONS16(pvx, 0, xqE, TB, buf);                                       \
        }                                                                     \
        FLUSHM(TB, buf);                                                      \
      }                                                                       \
    }

    unsigned xqA[16], xqB[16], xqC[16], xqD[16], xqE[16];

    // step-0 bounds + payloads + across-barrier prefetch of both b0's
    int e00 = __builtin_amdgcn_readlane(ebv, 0);
    int e01 = __builtin_amdgcn_readlane(ebv, 1);
    int e10 = __builtin_amdgcn_readlane(ebv, 2);
    int e11 = __builtin_amdgcn_readlane(ebv, 3);
    int pv0 = (int)payload[e00 + lane];
    int pv1 = (int)payload[e10 + lane];
    ISSUE16(xqA, pv0, 0);
    ISSUE16(xqC, pv1, 0);

    for (int s = 0; s < 8; ++s) {
      const int buf = s & 1;
      int cnt0 = e01 - e00, cnt1 = e11 - e10;

      // early in-step issues: b1 of both runs, b2 of run0
      if (cnt0 > 16) ISSUE16(xqB, pv0, 16);
      if (cnt1 > 16) ISSUE16(xqD, pv1, 16);
      if (cnt0 > 32) ISSUE16(xqE, pv0, 32);

      // next step's payload chunks early (latency hidden under consume)
      int f00 = e00, f01 = e01, f10 = e10, f11 = e11;
      int pvn0 = pv0, pvn1 = pv1;
      if (s < 7) {
        f00 = __builtin_amdgcn_readlane(ebv, (s + 1) * 4 + 0);
        f01 = __builtin_amdgcn_readlane(ebv, (s + 1) * 4 + 1);
        f10 = __builtin_amdgcn_readlane(ebv, (s + 1) * 4 + 2);
        f11 = __builtin_amdgcn_readlane(ebv, (s + 1) * 4 + 3);
        pvn0 = (int)payload[f00 + lane];
        pvn1 = (int)payload[f10 + lane];
      }

      // zero my slice (32 rows x 128 dims): 8 ds_write_b128/lane
      {
        short8 z = {0, 0, 0, 0, 0, 0, 0, 0};
#pragma unroll
        for (int i = 0; i < 8; ++i)
          *(short8*)&agg[buf][p][i * 4 + q][m16 * 8] = z;
      }

      RUNX(pv0, e00, e01, cnt0, xqA, xqB, 0);
      if (cnt1 > 32) ISSUE16(xqE, pv1, 32);   // r1.b2 flies under r1.b0/b1 consume
      RUNX(pv1, e10, e11, cnt1, xqC, xqD, 16);

      if (s < 7) {                            // across-barrier prefetch b0's
        e00 = f00; e01 = f01; e10 = f10; e11 = f11;
        pv0 = pvn0; pv1 = pvn1;
        ISSUE16(xqA, pv0, 0);
        ISSUE16(xqC, pv1, 0);
      }
      lds_barrier();                          // NO vmcnt drain: prefetch flies
    }
#undef RUNX
#undef CONS16
#undef CONSUME1
#undef FLUSHM
#undef ISSUE16
    return;                                   // producers exit; 8 barriers done
  }

  // ======================= CONSUMER =======================
  const int c = wave - 2;                 // owns cols c*64 .. c*64+64
  f32x4 acc[2][4];
#pragma unroll
  for (int t = 0; t < 2; ++t)
#pragma unroll
    for (int i = 0; i < 4; ++i) acc[t][i] = (f32x4){0.f, 0.f, 0.f, 0.f};

  for (int s = 0; s < 8; ++s) {
    lds_barrier();                        // barrier s: agg[s&1] ready
#pragma unroll
    for (int rp = 0; rp < 2; ++rp) {
      int rel = s * 2 + rp;
      short8 Bf[4][4];
#pragma unroll
      for (int kk = 0; kk < 4; ++kk)
#pragma unroll
        for (int i = 0; i < 4; ++i)
          Bf[kk][i] = *(const short8*)(Bs +
              ((size_t)((rel * 4 + kk) * 8 + (c * 4 + i)) << 9) + lane * 8);
#pragma unroll
      for (int kk = 0; kk < 4; ++kk) {
        short8 A0 = *(const short8*)&agg[s & 1][rp][m16][kk * 32 + q * 8];
        short8 A1 = *(const short8*)&agg[s & 1][rp][16 + m16][kk * 32 + q * 8];
#pragma unroll
        for (int i = 0; i < 4; ++i) {
          acc[0][i] = __builtin_amdgcn_mfma_f32_16x16x32_bf16(A0, Bf[kk][i], acc[0][i], 0, 0, 0);
          acc[1][i] = __builtin_amdgcn_mfma_f32_16x16x32_bf16(A1, Bf[kk][i], acc[1][i], 0, 0, 0);
        }
      }
    }
  }

  // ---- root (rel index 16): A from global xh rows of this block ----
  {
    short8 Bf[4][4];
#pragma unroll
    for (int kk = 0; kk < 4; ++kk)
#pragma unroll
      for (int i = 0; i < 4; ++i)
        Bf[kk][i] = *(const short8*)(Bs +
            ((size_t)((16 * 4 + kk) * 8 + (c * 4 + i)) << 9) + lane * 8);
    int r0 = tile0 * 16 + m16;      if (r0 > N_NODES) r0 = N_NODES;
    int r1 = tile0 * 16 + 16 + m16; if (r1 > N_NODES) r1 = N_NODES;
#pragma unroll
    for (int kk = 0; kk < 4; ++kk) {
      short8 A0 = *(const short8*)(xh + (size_t)r0 * HID + kk * 32 + q * 8);
      short8 A1 = *(const short8*)(xh + (size_t)r1 * HID + kk * 32 + q * 8);
#pragma unroll
      for (int i = 0; i < 4; ++i) {
        acc[0][i] = __builtin_amdgcn_mfma_f32_16x16x32_bf16(A0, Bf[kk][i], acc[0][i], 0, 0, 0);
        acc[1][i] = __builtin_amdgcn_mfma_f32_16x16x32_bf16(A1, Bf[kk][i], acc[1][i], 0, 0, 0);
      }
    }
  }

  // ---- epilogue: bias (+relu+bf16 or f32). C/D: col=lane&15, row=q*4+reg
  float bvv[4];
#pragma unroll
  for (int i = 0; i < 4; ++i) bvv[i] = bias[(c * 4 + i) * 16 + m16];
  int rbase = tile0 * 16 + q * 4;
#pragma unroll
  for (int t = 0; t < 2; ++t)
#pragma unroll
    for (int rg = 0; rg < 4; ++rg) {
      int row = rbase + t * 16 + rg;
      if (row < N_NODES) {
#pragma unroll
        for (int i = 0; i < 4; ++i) {
          float v = acc[t][i][rg] + bvv[i];
          int col = (c * 4 + i) * 16 + m16;
          if (write_f32) {
            fout[(size_t)row * HID + col] = v;
          } else {
            v = fmaxf(v, 0.f);
            union { __hip_bfloat16 h; ushort_t u; } cv;
            cv.h = __float2bfloat16(v);
            xh_out[(size_t)row * HID + col] = cv.u;
          }
        }
      }
    }
}

// ---------------- host ----------------

extern "C" void kernel_launch(void* const* d_in, const int* in_sizes, int n_in,
                              void* d_out, int out_size, void* d_ws, size_t ws_size,
                              hipStream_t stream) {
  const int*   ei        = (const int*)d_in[0];     // (2, E) int32
  const int*   et        = (const int*)d_in[1];     // (E,)   int32
  const float* node_init = (const float*)d_in[2];   // (N, H) f32
  const float* W         = (const float*)d_in[3];   // (3, 16, H, H) f32
  const float* root      = (const float*)d_in[4];   // (3, H, H) f32
  const float* bias      = (const float*)d_in[5];   // (3, H) f32
  float* outp = (float*)d_out;

  char* ws = (char*)d_ws;
  size_t o = 0;
  auto carve = [&](size_t bytes) { char* p = ws + o; o = (o + bytes + 255) & ~(size_t)255; return p; };
  ushort_t* xh_a       = (ushort_t*)carve((size_t)(N_NODES + 1) * HID * 2);   // +dummy row
  ushort_t* xh_b       = (ushort_t*)carve((size_t)(N_NODES + 1) * HID * 2);
  unsigned* payload    = (unsigned*)carve((size_t)PAYLOAD_CAP * 4);
  int*      cnt        = (int*)     carve((size_t)N_BINS * 4);
  int*      fine_start = (int*)     carve((size_t)N_BINS * 4);
  int*      rank       = (int*)     carve((size_t)N_EDGES * 4);
  int*      run_start  = (int*)     carve((size_t)(N_RUNS + 1) * 4);
  int*      totals     = (int*)     carve((size_t)N_SCANBLK * 4);
  ushort_t* Bs         = (ushort_t*)carve((size_t)3 * BS_LAYER * 2);
  (void)ws_size; (void)n_in; (void)in_sizes; (void)out_size;

  // ---- setup: padded counting sort by (tile, rel, m) + B swizzle ----
  hipMemsetAsync(cnt, 0, (size_t)N_BINS * 4, stream);
  hipLaunchKernelGGL(k_hist,        dim3(N_EDGES / 256), dim3(256), 0, stream, ei, et, cnt, rank);
  hipLaunchKernelGGL(k_runpad,      dim3((N_RUNS + 255) / 256), dim3(256), 0, stream, cnt, run_start);
  hipLaunchKernelGGL(k_btot,        dim3(N_SCANBLK), dim3(256), 0, stream, run_start, totals, N_RUNS);
  hipLaunchKernelGGL(k_scan_totals, dim3(1), dim3(1024), 0, stream, totals, run_start + N_RUNS, N_SCANBLK);
  hipLaunchKernelGGL(k_scan_within, dim3(N_SCANBLK), dim3(1024), 0, stream, run_start, totals, N_RUNS);
  hipLaunchKernelGGL(k_fineoff,     dim3((N_RUNS + 255) / 256), dim3(256), 0, stream, cnt, run_start, fine_start, payload);
  hipLaunchKernelGGL(k_sort,        dim3(N_EDGES / 256), dim3(256), 0, stream, ei, et, cnt, fine_start, rank, payload);
  hipLaunchKernelGGL(k_bt,          dim3(3 * 544 * 64 / 256), dim3(256), 0, stream, W, root, Bs);
  hipLaunchKernelGGL(k_xh,          dim3(N_NODES * HID / 4 / 256), dim3(256), 0, stream, node_init, xh_a);
  hipLaunchKernelGGL(k_zrow,        dim3(1), dim3(256), 0, stream, xh_a, xh_b);

  // ---- 3 layers, bf16 ping-pong; relu fused into epilogue of layers 0,1 ----
  hipLaunchKernelGGL(k_main, dim3(N_MBLK), dim3(256), 0, stream,
                     xh_a, xh_b, (float*)nullptr,
                     Bs + (size_t)0 * BS_LAYER, bias + 0 * HID, run_start, payload, 0);
  hipLaunchKernelGGL(k_main, dim3(N_MBLK), dim3(256), 0, stream,
                     xh_b, xh_a, (float*)nullptr,
                     Bs + (size_t)1 * BS_LAYER, bias + 1 * HID, run_start, payload, 0);
  hipLaunchKernelGGL(k_main, dim3(N_MBLK), dim3(256), 0, stream,
                     xh_a, (ushort_t*)nullptr, outp,
                     Bs + (size_t)2 * BS_LAYER, bias + 2 * HID, run_start, payload, 1);
}